// Round 1
// baseline (330.009 us; speedup 1.0000x reference)
//
#include <hip/hip_runtime.h>

typedef _Float16 half8 __attribute__((ext_vector_type(8)));
typedef float    f32x4 __attribute__((ext_vector_type(4)));

#define NB   8
#define NC   64
#define NH   256
#define NW   256
#define NO   64
// ws layout (bytes) — y intermediate eliminated; only weights + scale remain
#define TW_OFF   0ull
#define TW_BYTES (576ull * 64ull * 2ull)       // pre-swizzled ternary weights
#define MSW_OFF  (TW_OFF + TW_BYTES)

// ---------------------------------------------------------------------------
// Kernel 1: weight scale + ternary quantize, pre-arranged for MFMA A-fragments.
// tw2 position for W element (o,c,kh,kw):  k = (kh*3+kw)*64 + c
//   pos = ((k>>3)*64 + o)*8 + (k&7)   -> lane A-fragment = contiguous half8
// (unchanged from verified version)
// ---------------------------------------------------------------------------
__global__ __launch_bounds__(256) void wq_kernel(const float* __restrict__ W,
                                                 _Float16* __restrict__ tw2,
                                                 float* __restrict__ msw_out) {
    __shared__ float red[256];
    __shared__ float sw_sh;
    int tid = threadIdx.x;
    float s = 0.0f;
    #pragma unroll
    for (int i = 0; i < 144; ++i) s += fabsf(W[i * 256 + tid]);
    red[tid] = s;
    __syncthreads();
    for (int off = 128; off > 0; off >>= 1) {
        if (tid < off) red[tid] += red[tid + off];
        __syncthreads();
    }
    if (tid == 0) {
        float mean = red[0] / 36864.0f;
        float msw  = fmaxf(mean, 1e-8f);   // = 1/s_w
        sw_sh      = 1.0f / msw;           // = s_w
        msw_out[0] = msw;
    }
    __syncthreads();
    float s_w = sw_sh;
    #pragma unroll
    for (int i = 0; i < 144; ++i) {
        int idx = i * 256 + tid;                 // ((o*64+c)*3+kh)*3+kw
        float t = rintf(s_w * W[idx]);
        t = fminf(1.0f, fmaxf(-1.0f, t));
        int o  = idx / 576;
        int r  = idx - o * 576;
        int c  = r / 9;
        int r2 = r - c * 9;
        int kh = r2 / 3;
        int kw = r2 - kh * 3;
        int k  = (kh * 3 + kw) * 64 + c;
        tw2[((k >> 3) * 64 + o) * 8 + (k & 7)] = (_Float16)t;
    }
}

// ---------------------------------------------------------------------------
// Kernel 2 (FUSED): per-pixel channel-norm + int8 fake-quant computed in-block
// for this block's 3x66 halo pixels directly from x (NCHW f32), staged to LDS
// as f16, then 3x3 conv as implicit GEMM on mfma_f32_16x16x32_f16.
// Eliminates the 67 MB y intermediate (write + re-read) of the split version.
//
// Block = (b, h, 64-wide w tile), 4 waves; wave wv owns o in [wv*16, wv*16+16).
// LDS tile layout [kh][c/8][w(66)][8] so B-fragments are single b128 reads.
// XCD swizzle: 8192 blocks = 8 XCDs x 1024; physical%8 selects the image,
// so each XCD streams one full image -> halo row re-reads are per-XCD L2 hits.
// ---------------------------------------------------------------------------
__global__ __launch_bounds__(256, 3) void fused_kernel(const float* __restrict__ x,
                                                       const _Float16* __restrict__ tw2,
                                                       const float* __restrict__ msw_p,
                                                       const float* __restrict__ bias,
                                                       float* __restrict__ out) {
    __shared__ alignas(16) _Float16 lds[3 * 8 * 66 * 8];   // 25344 B

    int tid = threadIdx.x;
    int pb  = blockIdx.x;
    int bid = (pb & 7) * 1024 + (pb >> 3);       // bijective: 8192 % 8 == 0
    int wt = bid & 3;
    int h  = (bid >> 2) & 255;
    int bb = bid >> 10;
    int w0 = wt * 64;

    // ---- fused norm+quant staging: thread t owns halo pixel (kh=t/66, wl=t%66)
    if (tid < 198) {
        int kh = tid / 66;
        int wl = tid - kh * 66;
        int hp = h + kh - 1;
        int wp = w0 + wl - 1;
        float v[64];
        float s = 0.0f;
        if ((unsigned)hp < 256u && (unsigned)wp < 256u) {
            const float* xp = x + (size_t)bb * 64 * 65536 + (size_t)hp * 256 + wp;
            #pragma unroll
            for (int c = 0; c < 64; ++c) { v[c] = xp[(size_t)c * 65536]; s += v[c]; }
        } else {
            #pragma unroll
            for (int c = 0; c < 64; ++c) v[c] = 0.0f;   // pad pixel -> quantizes to 0
        }
        float mu = s * (1.0f / 64.0f);
        float var = 0.0f, dmax = 0.0f;
        #pragma unroll
        for (int c = 0; c < 64; ++c) {
            float d = v[c] - mu;
            var += d * d;
            dmax = fmaxf(dmax, fabsf(d));
        }
        var *= (1.0f / 64.0f);
        float r    = 1.0f / sqrtf(var + 1e-8f);
        float amax = fmaxf(dmax * r, 1e-8f);
        float s_a  = 127.0f / amax;
        float invs = amax / 127.0f;
        #pragma unroll
        for (int cc = 0; cc < 8; ++cc) {
            half8 hv;
            #pragma unroll
            for (int j = 0; j < 8; ++j) {
                float yn = (v[cc * 8 + j] - mu) * r;
                float q  = rintf(s_a * yn);                  // RNE == jnp.round
                q = fminf(127.0f, fmaxf(-128.0f, q));
                hv[j] = (_Float16)(q * invs);
            }
            *(half8*)(lds + ((kh * 8 + cc) * 66 + wl) * 8) = hv;
        }
    }

    int l   = tid & 63;
    int wv  = tid >> 6;
    int l15 = l & 15;
    int q8  = l >> 4;

    // ---- preload weight A-fragments (18 K-steps), L2-hot ----
    half8 aw[18];
    #pragma unroll
    for (int ks = 0; ks < 18; ++ks)
        aw[ks] = *(const half8*)(tw2 + (((ks * 4 + q8) * 64) + wv * 16 + l15) * 8);

    __syncthreads();

    f32x4 acc[4];
    #pragma unroll
    for (int nt = 0; nt < 4; ++nt)
        #pragma unroll
        for (int r2 = 0; r2 < 4; ++r2) acc[nt][r2] = 0.0f;

    #pragma unroll
    for (int ks = 0; ks < 18; ++ks) {
        int tap = ks >> 1;
        int kh  = tap / 3;
        int kw  = tap - kh * 3;
        int ccb = (ks & 1) * 4 + q8;
        int base = ((kh * 8 + ccb) * 66 + kw + l15) * 8;
        #pragma unroll
        for (int nt = 0; nt < 4; ++nt) {
            half8 bf = *(const half8*)(lds + base + nt * 128);
            acc[nt] = __builtin_amdgcn_mfma_f32_16x16x32_f16(aw[ks], bf, acc[nt], 0, 0, 0);
        }
    }

    // ---- epilogue: D[row=o_local=q8*4+reg][col=w=nt*16+l15] ----
    float msw = *msw_p;                 // = 1/s_w
    size_t obase = ((size_t)bb * 64) * 65536 + (size_t)h * 256;
    #pragma unroll
    for (int reg = 0; reg < 4; ++reg) {
        int o = wv * 16 + q8 * 4 + reg;
        float bo = bias[o];
        #pragma unroll
        for (int nt = 0; nt < 4; ++nt) {
            int w = w0 + nt * 16 + l15;
            out[obase + (size_t)o * 65536 + w] = acc[nt][reg] * msw + bo;
        }
    }
}

extern "C" void kernel_launch(void* const* d_in, const int* in_sizes, int n_in,
                              void* d_out, int out_size, void* d_ws, size_t ws_size,
                              hipStream_t stream) {
    const float* x = (const float*)d_in[0];   // [8,64,256,256]
    const float* W = (const float*)d_in[1];   // [64,64,3,3]
    const float* b = (const float*)d_in[2];   // [64]
    float* out = (float*)d_out;

    char* ws = (char*)d_ws;
    _Float16* tw2 = (_Float16*)(ws + TW_OFF);
    float*    msw = (float*)(ws + MSW_OFF);

    wq_kernel<<<1, 256, 0, stream>>>(W, tw2, msw);
    fused_kernel<<<8192, 256, 0, stream>>>(x, tw2, msw, b, out);
}

// Round 2
// 313.550 us; speedup vs baseline: 1.0525x; 1.0525x over previous
//
#include <hip/hip_runtime.h>

typedef _Float16 half8 __attribute__((ext_vector_type(8)));
typedef float    f32x4 __attribute__((ext_vector_type(4)));

#define NB   8
#define NC   64
#define NH   256
#define NW   256
#define NO   64
// ws layout (bytes)
#define TW_OFF   0ull
#define TW_BYTES (576ull * 64ull * 2ull)       // pre-swizzled ternary weights
#define MSW_OFF  (TW_OFF + TW_BYTES)           // 1 float
#define PART_OFF (MSW_OFF + 16ull)             // 144 floats of |W| partial sums

// ---------------------------------------------------------------------------
// Kernel 1a: |W| partial sums. 144 blocks x 256 threads, 1 element each.
// ---------------------------------------------------------------------------
__global__ __launch_bounds__(256) void wsum_kernel(const float* __restrict__ W,
                                                   float* __restrict__ partial) {
    __shared__ float red[256];
    int tid = threadIdx.x;
    red[tid] = fabsf(W[blockIdx.x * 256 + tid]);
    __syncthreads();
    for (int off = 128; off > 0; off >>= 1) {
        if (tid < off) red[tid] += red[tid + off];
        __syncthreads();
    }
    if (tid == 0) partial[blockIdx.x] = red[0];
}

// ---------------------------------------------------------------------------
// Kernel 1b: finish mean(|W|), ternary-quantize, store pre-swizzled for MFMA.
// tw2 position for W element (o,c,kh,kw):  k = (kh*3+kw)*64 + c
//   pos = ((k>>3)*64 + o)*8 + (k&7)   -> lane A-fragment = contiguous half8
// 144 blocks x 256 threads, 1 element each (each block redundantly folds the
// 144 partials -- cheap, avoids atomics/zero-init of poisoned ws).
// ---------------------------------------------------------------------------
__global__ __launch_bounds__(256) void wq2_kernel(const float* __restrict__ W,
                                                  const float* __restrict__ partial,
                                                  _Float16* __restrict__ tw2,
                                                  float* __restrict__ msw_out) {
    __shared__ float red[256];
    int tid = threadIdx.x;
    red[tid] = (tid < 144) ? partial[tid] : 0.0f;
    __syncthreads();
    for (int off = 128; off > 0; off >>= 1) {
        if (tid < off) red[tid] += red[tid + off];
        __syncthreads();
    }
    float mean = red[0] / 36864.0f;
    float msw  = fmaxf(mean, 1e-8f);   // = 1/s_w
    float s_w  = 1.0f / msw;
    if (blockIdx.x == 0 && tid == 0) msw_out[0] = msw;

    int idx = blockIdx.x * 256 + tid;            // ((o*64+c)*3+kh)*3+kw
    float t = rintf(s_w * W[idx]);
    t = fminf(1.0f, fmaxf(-1.0f, t));
    int o  = idx / 576;
    int r  = idx - o * 576;
    int c  = r / 9;
    int r2 = r - c * 9;
    int kh = r2 / 3;
    int kw = r2 - kh * 3;
    int k  = (kh * 3 + kw) * 64 + c;
    tw2[((k >> 3) * 64 + o) * 8 + (k & 7)] = (_Float16)t;
}

// ---------------------------------------------------------------------------
// Kernel 2 (FUSED): per-pixel channel-norm + int8 fake-quant for this block's
// 3x66 halo, staged to LDS f16, then 3x3 conv as implicit GEMM (16x16x32 f16).
//
// Norm phase is STREAMING: pass 1 loads x once (raw f16 parked in the final
// LDS slot), tracking sum / sum-sq / min / max in ~8 registers
// (var = E[x^2]-mu^2, dmax = max(mx-mu, mu-mn)); pass 2 quantizes the LDS
// tile in place. No v[64] register array -> no remat/spill chains (the
// round-1 VGPR=52 pathology).
//
// Block = (b, h, 64-wide w tile), 4 waves; wave wv owns o in [wv*16, wv*16+16).
// LDS tile layout [kh][c/8][w(66)][8] so B-fragments are single b128 reads.
// XCD swizzle: 8192 blocks = 8 XCDs x 1024; physical%8 selects the image.
// ---------------------------------------------------------------------------
__global__ __launch_bounds__(256, 4) void fused_kernel(const float* __restrict__ x,
                                                       const _Float16* __restrict__ tw2,
                                                       const float* __restrict__ msw_p,
                                                       const float* __restrict__ bias,
                                                       float* __restrict__ out) {
    __shared__ alignas(16) _Float16 lds[3 * 8 * 66 * 8];   // 25344 B

    int tid = threadIdx.x;
    int pb  = blockIdx.x;
    int bid = (pb & 7) * 1024 + (pb >> 3);       // bijective: 8192 % 8 == 0
    int wt = bid & 3;
    int h  = (bid >> 2) & 255;
    int bb = bid >> 10;
    int w0 = wt * 64;

    if (tid < 198) {
        int kh = tid / 66;
        int wl = tid - kh * 66;
        int hp = h + kh - 1;
        int wp = w0 + wl - 1;
        int inb = ((unsigned)hp < 256u) & ((unsigned)wp < 256u);
        int hpc = min(max(hp, 0), 255);
        int wpc = min(max(wp, 0), 255);
        const float* xp = x + (size_t)bb * 64 * 65536 + (size_t)hpc * 256 + wpc;
        float fin = (float)inb;

        // ---- pass 1: stream x, park raw f16, accumulate stats ----
        float s = 0.0f, sq = 0.0f, mn = 1e30f, mx = -1e30f;
        #pragma unroll
        for (int cc = 0; cc < 8; ++cc) {
            half8 hv;
            #pragma unroll
            for (int j = 0; j < 8; ++j) {
                float v = xp[(size_t)(cc * 8 + j) * 65536] * fin;
                s  += v;
                sq += v * v;
                mn = fminf(mn, v);
                mx = fmaxf(mx, v);
                hv[j] = (_Float16)v;
            }
            *(half8*)(lds + ((kh * 8 + cc) * 66 + wl) * 8) = hv;
        }
        float mu  = s * (1.0f / 64.0f);
        float var = fmaxf(sq * (1.0f / 64.0f) - mu * mu, 0.0f);
        float r    = 1.0f / sqrtf(var + 1e-8f);
        float dmax = fmaxf(mx - mu, mu - mn);
        float amax = fmaxf(dmax * r, 1e-8f);
        float s_a  = 127.0f / amax;
        float invs = amax / 127.0f;

        // ---- pass 2: quantize the parked tile in place ----
        #pragma unroll
        for (int cc = 0; cc < 8; ++cc) {
            half8 hv = *(half8*)(lds + ((kh * 8 + cc) * 66 + wl) * 8);
            #pragma unroll
            for (int j = 0; j < 8; ++j) {
                float yn = ((float)hv[j] - mu) * r;
                float q  = rintf(s_a * yn);                  // RNE == jnp.round
                q = fminf(127.0f, fmaxf(-128.0f, q));
                hv[j] = (_Float16)(q * invs);
            }
            *(half8*)(lds + ((kh * 8 + cc) * 66 + wl) * 8) = hv;
        }
    }

    int l   = tid & 63;
    int wv  = tid >> 6;
    int l15 = l & 15;
    int q8  = l >> 4;

    // ---- preload weight A-fragments (18 K-steps), L2-hot ----
    half8 aw[18];
    #pragma unroll
    for (int ks = 0; ks < 18; ++ks)
        aw[ks] = *(const half8*)(tw2 + (((ks * 4 + q8) * 64) + wv * 16 + l15) * 8);

    __syncthreads();

    f32x4 acc[4];
    #pragma unroll
    for (int nt = 0; nt < 4; ++nt)
        #pragma unroll
        for (int r2 = 0; r2 < 4; ++r2) acc[nt][r2] = 0.0f;

    #pragma unroll
    for (int ks = 0; ks < 18; ++ks) {
        int tap = ks >> 1;
        int kh  = tap / 3;
        int kw  = tap - kh * 3;
        int ccb = (ks & 1) * 4 + q8;
        int base = ((kh * 8 + ccb) * 66 + kw + l15) * 8;
        #pragma unroll
        for (int nt = 0; nt < 4; ++nt) {
            half8 bf = *(const half8*)(lds + base + nt * 128);
            acc[nt] = __builtin_amdgcn_mfma_f32_16x16x32_f16(aw[ks], bf, acc[nt], 0, 0, 0);
        }
    }

    // ---- epilogue: D[row=o_local=q8*4+reg][col=w=nt*16+l15] ----
    float msw = *msw_p;                 // = 1/s_w
    size_t obase = ((size_t)bb * 64) * 65536 + (size_t)h * 256;
    #pragma unroll
    for (int reg = 0; reg < 4; ++reg) {
        int o = wv * 16 + q8 * 4 + reg;
        float bo = bias[o];
        #pragma unroll
        for (int nt = 0; nt < 4; ++nt) {
            int w = w0 + nt * 16 + l15;
            out[obase + (size_t)o * 65536 + w] = acc[nt][reg] * msw + bo;
        }
    }
}

extern "C" void kernel_launch(void* const* d_in, const int* in_sizes, int n_in,
                              void* d_out, int out_size, void* d_ws, size_t ws_size,
                              hipStream_t stream) {
    const float* x = (const float*)d_in[0];   // [8,64,256,256]
    const float* W = (const float*)d_in[1];   // [64,64,3,3]
    const float* b = (const float*)d_in[2];   // [64]
    float* out = (float*)d_out;

    char* ws = (char*)d_ws;
    _Float16* tw2  = (_Float16*)(ws + TW_OFF);
    float*    msw  = (float*)(ws + MSW_OFF);
    float*    part = (float*)(ws + PART_OFF);

    wsum_kernel<<<144, 256, 0, stream>>>(W, part);
    wq2_kernel<<<144, 256, 0, stream>>>(W, part, tw2, msw);
    fused_kernel<<<8192, 256, 0, stream>>>(x, tw2, msw, b, out);
}

// Round 3
// 284.995 us; speedup vs baseline: 1.1579x; 1.1002x over previous
//
#include <hip/hip_runtime.h>

typedef _Float16 half8 __attribute__((ext_vector_type(8)));
typedef float    f32x4 __attribute__((ext_vector_type(4)));

#define NB   8
#define NC   64
#define NH   256
#define NW   256
#define NO   64
#define HT   4                                  // output rows per block
// ws layout (bytes)
#define TW_OFF   0ull
#define TW_BYTES (576ull * 64ull * 2ull)       // pre-swizzled ternary weights
#define MSW_OFF  (TW_OFF + TW_BYTES)           // 1 float
#define PART_OFF (MSW_OFF + 16ull)             // 144 floats of |W| partial sums

// ---------------------------------------------------------------------------
// Kernel 1a: |W| partial sums. 144 blocks x 256 threads, 1 element each.
// ---------------------------------------------------------------------------
__global__ __launch_bounds__(256) void wsum_kernel(const float* __restrict__ W,
                                                   float* __restrict__ partial) {
    __shared__ float red[256];
    int tid = threadIdx.x;
    red[tid] = fabsf(W[blockIdx.x * 256 + tid]);
    __syncthreads();
    for (int off = 128; off > 0; off >>= 1) {
        if (tid < off) red[tid] += red[tid + off];
        __syncthreads();
    }
    if (tid == 0) partial[blockIdx.x] = red[0];
}

// ---------------------------------------------------------------------------
// Kernel 1b: finish mean(|W|), ternary-quantize, store pre-swizzled for MFMA.
// tw2 position for W element (o,c,kh,kw):  k = (kh*3+kw)*64 + c
//   pos = ((k>>3)*64 + o)*8 + (k&7)   -> lane A-fragment = contiguous half8
// ---------------------------------------------------------------------------
__global__ __launch_bounds__(256) void wq2_kernel(const float* __restrict__ W,
                                                  const float* __restrict__ partial,
                                                  _Float16* __restrict__ tw2,
                                                  float* __restrict__ msw_out) {
    __shared__ float red[256];
    int tid = threadIdx.x;
    red[tid] = (tid < 144) ? partial[tid] : 0.0f;
    __syncthreads();
    for (int off = 128; off > 0; off >>= 1) {
        if (tid < off) red[tid] += red[tid + off];
        __syncthreads();
    }
    float mean = red[0] / 36864.0f;
    float msw  = fmaxf(mean, 1e-8f);   // = 1/s_w
    float s_w  = 1.0f / msw;
    if (blockIdx.x == 0 && tid == 0) msw_out[0] = msw;

    int idx = blockIdx.x * 256 + tid;            // ((o*64+c)*3+kh)*3+kw
    float t = rintf(s_w * W[idx]);
    t = fminf(1.0f, fmaxf(-1.0f, t));
    int o  = idx / 576;
    int r  = idx - o * 576;
    int c  = r / 9;
    int r2 = r - c * 9;
    int kh = r2 / 3;
    int kw = r2 - kh * 3;
    int k  = (kh * 3 + kw) * 64 + c;
    tw2[((k >> 3) * 64 + o) * 8 + (k & 7)] = (_Float16)t;
}

// ---------------------------------------------------------------------------
// Kernel 2 (FUSED, multi-row): per-pixel channel-norm + int8 fake-quant for
// this block's 6x66 halo, staged to LDS f16, then 3x3 conv as implicit GEMM
// (16x16x32 f16) over HT=4 output rows.
//
// Round-2 lesson: norm VALU (~830 ops/px) with a 3x halo redundancy was the
// 68-us floor. HT=4 rows/block cuts redundancy 3.09x -> 1.55x; aw fragments
// are reused across all 4 rows.
//
// Block = (b, 4-row h tile, 64-wide w tile) -> grid 2048 = 8 XCDs x 1 image.
// LDS [kh=6][c/8][w(66)][8] f16 = 50688 B (3 blocks/CU).
// 4 waves; wave wv owns o in [wv*16, wv*16+16); rows processed sequentially.
// ---------------------------------------------------------------------------
__global__ __launch_bounds__(256, 3) void fused_kernel(const float* __restrict__ x,
                                                       const _Float16* __restrict__ tw2,
                                                       const float* __restrict__ msw_p,
                                                       const float* __restrict__ bias,
                                                       float* __restrict__ out) {
    __shared__ alignas(16) _Float16 lds[6 * 8 * 66 * 8];   // 50688 B

    int tid = threadIdx.x;
    int pb  = blockIdx.x;
    int bid = (pb & 7) * 256 + (pb >> 3);   // bijective: 2048 = 8 x 256; XCD i -> image i
    int wt = bid & 3;
    int ht = (bid >> 2) & 63;
    int bb = bid >> 8;
    int h0 = ht * HT;
    int w0 = wt * 64;

    // ---- fused norm+quant staging: 396 halo pixels (6 rows x 66) ----
    for (int p = tid; p < 396; p += 256) {
        int kh = p / 66;                    // 0..5
        int wl = p - kh * 66;
        int hp = h0 + kh - 1;
        int wp = w0 + wl - 1;
        _Float16* slot = lds + kh * 4224 + wl * 8;   // + cc*528

        if (((unsigned)hp >= 256u) | ((unsigned)wp >= 256u)) {
            half8 z;
            #pragma unroll
            for (int j = 0; j < 8; ++j) z[j] = (_Float16)0.0f;
            #pragma unroll
            for (int cc = 0; cc < 8; ++cc) *(half8*)(slot + cc * 528) = z;
            continue;
        }
        const float* xp = x + (size_t)bb * 4194304 + (size_t)hp * 256 + wp;

        // pass 1: stream x, park raw f16, accumulate stats
        float s = 0.0f, sq = 0.0f, mn = 1e30f, mx = -1e30f;
        #pragma unroll
        for (int cc = 0; cc < 8; ++cc) {
            half8 hv;
            #pragma unroll
            for (int j = 0; j < 8; ++j) {
                float v = xp[(size_t)(cc * 8 + j) * 65536];
                s  += v;
                sq += v * v;
                mn = fminf(mn, v);
                mx = fmaxf(mx, v);
                hv[j] = (_Float16)v;
            }
            *(half8*)(slot + cc * 528) = hv;
        }
        float mu  = s * (1.0f / 64.0f);
        float var = fmaxf(sq * (1.0f / 64.0f) - mu * mu, 0.0f);
        float r    = 1.0f / sqrtf(var + 1e-8f);
        float dmax = fmaxf(mx - mu, mu - mn);
        float amax = fmaxf(dmax * r, 1e-8f);
        float s_a  = 127.0f / amax;
        float invs = amax / 127.0f;
        float af   = s_a * r;
        float bf   = -mu * af;

        // pass 2: quantize the parked tile in place
        #pragma unroll
        for (int cc = 0; cc < 8; ++cc) {
            half8 hv = *(half8*)(slot + cc * 528);
            #pragma unroll
            for (int j = 0; j < 8; ++j) {
                float q = rintf(fmaf((float)hv[j], af, bf));  // RNE == jnp.round
                q = fminf(127.0f, fmaxf(-128.0f, q));
                hv[j] = (_Float16)(q * invs);
            }
            *(half8*)(slot + cc * 528) = hv;
        }
    }

    int l   = tid & 63;
    int wv  = tid >> 6;
    int l15 = l & 15;
    int q8  = l >> 4;

    // ---- preload weight A-fragments (18 K-steps), L2-hot, reused for 4 rows ----
    half8 aw[18];
    #pragma unroll
    for (int ks = 0; ks < 18; ++ks)
        aw[ks] = *(const half8*)(tw2 + (((ks * 4 + q8) * 64) + wv * 16 + l15) * 8);

    __syncthreads();

    float msw = *msw_p;                 // = 1/s_w
    #pragma unroll
    for (int r = 0; r < HT; ++r) {
        f32x4 acc[4];
        #pragma unroll
        for (int nt = 0; nt < 4; ++nt)
            #pragma unroll
            for (int r2 = 0; r2 < 4; ++r2) acc[nt][r2] = 0.0f;

        #pragma unroll
        for (int ks = 0; ks < 18; ++ks) {
            int tap = ks >> 1;
            int kh  = tap / 3;
            int kw  = tap - kh * 3;
            int ccb = (ks & 1) * 4 + q8;
            int base = (((kh + r) * 8 + ccb) * 66 + kw + l15) * 8;
            #pragma unroll
            for (int nt = 0; nt < 4; ++nt) {
                half8 bf = *(const half8*)(lds + base + nt * 128);
                acc[nt] = __builtin_amdgcn_mfma_f32_16x16x32_f16(aw[ks], bf, acc[nt], 0, 0, 0);
            }
        }

        // epilogue: D[row=o_local=q8*4+reg][col=w=nt*16+l15]
        size_t obase = ((size_t)bb * 64) * 65536 + (size_t)(h0 + r) * 256;
        #pragma unroll
        for (int reg = 0; reg < 4; ++reg) {
            int o = wv * 16 + q8 * 4 + reg;
            float bo = bias[o];
            #pragma unroll
            for (int nt = 0; nt < 4; ++nt) {
                int w = w0 + nt * 16 + l15;
                out[obase + (size_t)o * 65536 + w] = acc[nt][reg] * msw + bo;
            }
        }
    }
}

extern "C" void kernel_launch(void* const* d_in, const int* in_sizes, int n_in,
                              void* d_out, int out_size, void* d_ws, size_t ws_size,
                              hipStream_t stream) {
    const float* x = (const float*)d_in[0];   // [8,64,256,256]
    const float* W = (const float*)d_in[1];   // [64,64,3,3]
    const float* b = (const float*)d_in[2];   // [64]
    float* out = (float*)d_out;

    char* ws = (char*)d_ws;
    _Float16* tw2  = (_Float16*)(ws + TW_OFF);
    float*    msw  = (float*)(ws + MSW_OFF);
    float*    part = (float*)(ws + PART_OFF);

    wsum_kernel<<<144, 256, 0, stream>>>(W, part);
    wq2_kernel<<<144, 256, 0, stream>>>(W, part, tw2, msw);
    fused_kernel<<<2048, 256, 0, stream>>>(x, tw2, msw, b, out);
}

// Round 4
// 277.567 us; speedup vs baseline: 1.1889x; 1.0268x over previous
//
#include <hip/hip_runtime.h>

typedef _Float16 half8 __attribute__((ext_vector_type(8)));
typedef float    f32x4 __attribute__((ext_vector_type(4)));

#define NB   8
#define NC   64
#define NH   256
#define NW   256
#define NO   64
#define HT   4                                  // output rows per block
// ws layout (bytes)
#define TW_OFF   0ull
#define TW_BYTES (576ull * 64ull * 2ull)       // pre-swizzled ternary weights
#define MSW_OFF  (TW_OFF + TW_BYTES)           // 1 float
#define PART_OFF (MSW_OFF + 16ull)             // 144 floats of |W| partial sums

// ---------------------------------------------------------------------------
// Kernel 1a: |W| partial sums. 144 blocks x 256 threads, 1 element each.
// ---------------------------------------------------------------------------
__global__ __launch_bounds__(256) void wsum_kernel(const float* __restrict__ W,
                                                   float* __restrict__ partial) {
    __shared__ float red[256];
    int tid = threadIdx.x;
    red[tid] = fabsf(W[blockIdx.x * 256 + tid]);
    __syncthreads();
    for (int off = 128; off > 0; off >>= 1) {
        if (tid < off) red[tid] += red[tid + off];
        __syncthreads();
    }
    if (tid == 0) partial[blockIdx.x] = red[0];
}

// ---------------------------------------------------------------------------
// Kernel 1b: finish mean(|W|), ternary-quantize, store pre-swizzled for MFMA.
// tw2 position for W element (o,c,kh,kw):  k = (kh*3+kw)*64 + c
//   pos = ((k>>3)*64 + o)*8 + (k&7)   -> lane A-fragment = contiguous half8
// ---------------------------------------------------------------------------
__global__ __launch_bounds__(256) void wq2_kernel(const float* __restrict__ W,
                                                  const float* __restrict__ partial,
                                                  _Float16* __restrict__ tw2,
                                                  float* __restrict__ msw_out) {
    __shared__ float red[256];
    int tid = threadIdx.x;
    red[tid] = (tid < 144) ? partial[tid] : 0.0f;
    __syncthreads();
    for (int off = 128; off > 0; off >>= 1) {
        if (tid < off) red[tid] += red[tid + off];
        __syncthreads();
    }
    float mean = red[0] / 36864.0f;
    float msw  = fmaxf(mean, 1e-8f);   // = 1/s_w
    float s_w  = 1.0f / msw;
    if (blockIdx.x == 0 && tid == 0) msw_out[0] = msw;

    int idx = blockIdx.x * 256 + tid;            // ((o*64+c)*3+kh)*3+kw
    float t = rintf(s_w * W[idx]);
    t = fminf(1.0f, fmaxf(-1.0f, t));            // weight clamp IS needed
    int o  = idx / 576;
    int r  = idx - o * 576;
    int c  = r / 9;
    int r2 = r - c * 9;
    int kh = r2 / 3;
    int kw = r2 - kh * 3;
    int k  = (kh * 3 + kw) * 64 + c;
    tw2[((k >> 3) * 64 + o) * 8 + (k & 7)] = (_Float16)t;
}

// ---------------------------------------------------------------------------
// Kernel 2 (FUSED, multi-row, 2x2 wave split): norm + int8 fake-quant for the
// block's 6x66 halo staged to LDS f16, then 3x3 conv as implicit GEMM
// (16x16x32 f16) over HT=4 output rows.
//
// Round-3 lesson: all 4 waves read IDENTICAL B-fragments (waves differed only
// in o) -> 4x LDS-read amplification; conv LDS pipe (~46 us incl 4.1 cyc/read
// conflicts) was the largest consumer. Now each wave owns 2 o-groups x 2
// nt-quadrants: B-reads/wave halve, block-total conv ds_reads halve.
// aw[36] (144 VGPR) -> __launch_bounds__(256,2).
//
// Quantize clamps removed: |s_a*yn| <= s_a*amax = 127 by construction,
// so rintf result is already in [-127,127] (reference clips to [-128,127]).
//
// Block = (b, 4-row h tile, 64-wide w tile) -> grid 2048 = 8 XCDs x 1 image.
// LDS [kh=6][c/8][w(66)][8] f16 = 50688 B (2 blocks/CU with VGPR ~200).
// ---------------------------------------------------------------------------
__global__ __launch_bounds__(256, 2) void fused_kernel(const float* __restrict__ x,
                                                       const _Float16* __restrict__ tw2,
                                                       const float* __restrict__ msw_p,
                                                       const float* __restrict__ bias,
                                                       float* __restrict__ out) {
    __shared__ alignas(16) _Float16 lds[6 * 8 * 66 * 8];   // 50688 B

    int tid = threadIdx.x;
    int pb  = blockIdx.x;
    int bid = (pb & 7) * 256 + (pb >> 3);   // bijective: 2048 = 8 x 256; XCD i -> image i
    int wt = bid & 3;
    int ht = (bid >> 2) & 63;
    int bb = bid >> 8;
    int h0 = ht * HT;
    int w0 = wt * 64;

    int l   = tid & 63;
    int wv  = tid >> 6;
    int l15 = l & 15;
    int q8  = l >> 4;
    int ogp = wv >> 1;                      // o-pair index: o in [ogp*32, ogp*32+32)
    int ntp = wv & 1;                       // nt-pair index: w quadrants ntp*2, ntp*2+1

    // ---- preload weight A-fragments FIRST (prefetch under norm compute) ----
    // aw[ks*2+i] = A-fragment for K-step ks, o-group (ogp*2+i)
    half8 aw[36];
    #pragma unroll
    for (int ks = 0; ks < 18; ++ks) {
        #pragma unroll
        for (int i = 0; i < 2; ++i)
            aw[ks * 2 + i] =
                *(const half8*)(tw2 + (((ks * 4 + q8) * 64) + ogp * 32 + i * 16 + l15) * 8);
    }

    // ---- fused norm+quant staging: 396 halo pixels (6 rows x 66) ----
    for (int p = tid; p < 396; p += 256) {
        int kh = p / 66;                    // 0..5
        int wl = p - kh * 66;
        int hp = h0 + kh - 1;
        int wp = w0 + wl - 1;
        _Float16* slot = lds + kh * 4224 + wl * 8;   // + cc*528

        if (((unsigned)hp >= 256u) | ((unsigned)wp >= 256u)) {
            half8 z;
            #pragma unroll
            for (int j = 0; j < 8; ++j) z[j] = (_Float16)0.0f;
            #pragma unroll
            for (int cc = 0; cc < 8; ++cc) *(half8*)(slot + cc * 528) = z;
            continue;
        }
        const float* xp = x + (size_t)bb * 4194304 + (size_t)hp * 256 + wp;

        // pass 1: stream x, park raw f16, accumulate stats
        float s = 0.0f, sq = 0.0f, mn = 1e30f, mx = -1e30f;
        #pragma unroll
        for (int cc = 0; cc < 8; ++cc) {
            half8 hv;
            #pragma unroll
            for (int j = 0; j < 8; ++j) {
                float v = xp[(size_t)(cc * 8 + j) * 65536];
                s  += v;
                sq += v * v;
                mn = fminf(mn, v);
                mx = fmaxf(mx, v);
                hv[j] = (_Float16)v;
            }
            *(half8*)(slot + cc * 528) = hv;
        }
        float mu  = s * (1.0f / 64.0f);
        float var = fmaxf(sq * (1.0f / 64.0f) - mu * mu, 0.0f);
        float r    = 1.0f / sqrtf(var + 1e-8f);
        float dmax = fmaxf(mx - mu, mu - mn);
        float amax = fmaxf(dmax * r, 1e-8f);
        float s_a  = 127.0f / amax;
        float invs = amax / 127.0f;
        float af   = s_a * r;
        float bf   = -mu * af;

        // pass 2: quantize the parked tile in place (no clamp needed)
        #pragma unroll
        for (int cc = 0; cc < 8; ++cc) {
            half8 hv = *(half8*)(slot + cc * 528);
            #pragma unroll
            for (int j = 0; j < 8; ++j) {
                float q = rintf(fmaf((float)hv[j], af, bf));  // RNE == jnp.round
                hv[j] = (_Float16)(q * invs);
            }
            *(half8*)(slot + cc * 528) = hv;
        }
    }

    __syncthreads();

    float msw = *msw_p;                 // = 1/s_w
    #pragma unroll
    for (int r = 0; r < HT; ++r) {
        f32x4 acc[2][2];
        #pragma unroll
        for (int i = 0; i < 2; ++i)
            #pragma unroll
            for (int j = 0; j < 2; ++j)
                #pragma unroll
                for (int r2 = 0; r2 < 4; ++r2) acc[i][j][r2] = 0.0f;

        #pragma unroll
        for (int ks = 0; ks < 18; ++ks) {
            int tap = ks >> 1;
            int kh  = tap / 3;
            int kw  = tap - kh * 3;
            int ccb = (ks & 1) * 4 + q8;
            int base = (((kh + r) * 8 + ccb) * 66 + kw + l15) * 8;
            half8 b0 = *(const half8*)(lds + base + (ntp * 2 + 0) * 128);
            half8 b1 = *(const half8*)(lds + base + (ntp * 2 + 1) * 128);
            acc[0][0] = __builtin_amdgcn_mfma_f32_16x16x32_f16(aw[ks * 2 + 0], b0, acc[0][0], 0, 0, 0);
            acc[1][0] = __builtin_amdgcn_mfma_f32_16x16x32_f16(aw[ks * 2 + 1], b0, acc[1][0], 0, 0, 0);
            acc[0][1] = __builtin_amdgcn_mfma_f32_16x16x32_f16(aw[ks * 2 + 0], b1, acc[0][1], 0, 0, 0);
            acc[1][1] = __builtin_amdgcn_mfma_f32_16x16x32_f16(aw[ks * 2 + 1], b1, acc[1][1], 0, 0, 0);
        }

        // epilogue: D[row=o_local=q8*4+reg][col]
        size_t obase = ((size_t)bb * 64) * 65536 + (size_t)(h0 + r) * 256;
        #pragma unroll
        for (int i = 0; i < 2; ++i) {
            #pragma unroll
            for (int reg = 0; reg < 4; ++reg) {
                int o = ogp * 32 + i * 16 + q8 * 4 + reg;
                float bo = bias[o];
                #pragma unroll
                for (int j = 0; j < 2; ++j) {
                    int w = w0 + (ntp * 2 + j) * 16 + l15;
                    out[obase + (size_t)o * 65536 + w] = acc[i][j][reg] * msw + bo;
                }
            }
        }
    }
}

extern "C" void kernel_launch(void* const* d_in, const int* in_sizes, int n_in,
                              void* d_out, int out_size, void* d_ws, size_t ws_size,
                              hipStream_t stream) {
    const float* x = (const float*)d_in[0];   // [8,64,256,256]
    const float* W = (const float*)d_in[1];   // [64,64,3,3]
    const float* b = (const float*)d_in[2];   // [64]
    float* out = (float*)d_out;

    char* ws = (char*)d_ws;
    _Float16* tw2  = (_Float16*)(ws + TW_OFF);
    float*    msw  = (float*)(ws + MSW_OFF);
    float*    part = (float*)(ws + PART_OFF);

    wsum_kernel<<<144, 256, 0, stream>>>(W, part);
    wq2_kernel<<<144, 256, 0, stream>>>(W, part, tw2, msw);
    fused_kernel<<<2048, 256, 0, stream>>>(x, tw2, msw, b, out);
}